// Round 1
// baseline (1200.719 us; speedup 1.0000x reference)
//
#include <hip/hip_runtime.h>
#include <hip/hip_bf16.h>

#define N_PTS 400000
#define KOFF 27

typedef __attribute__((ext_vector_type(8))) short short8;
typedef __attribute__((ext_vector_type(4))) float float4v;

__device__ __forceinline__ unsigned short f2bf(float f) {
    union { float f; unsigned int u; } a; a.f = f;
    unsigned int u = a.u;
    unsigned int r = (u + 0x7FFFu + ((u >> 16) & 1u)) >> 16;
    return (unsigned short)r;
}

__device__ __forceinline__ float bf2f(unsigned short u) {
    union { unsigned int u; float f; } a; a.u = ((unsigned int)u) << 16;
    return a.f;
}

// ---- cast features fp32 -> bf16 ----
__global__ void cast_feat_kernel(const float* __restrict__ src,
                                 unsigned short* __restrict__ dst, int n4) {
    int i = blockIdx.x * blockDim.x + threadIdx.x;
    if (i >= n4) return;
    const float4* s4 = (const float4*)src;
    float4 v = s4[i];
    ushort4 o;
    o.x = f2bf(v.x); o.y = f2bf(v.y); o.z = f2bf(v.z); o.w = f2bf(v.w);
    ((ushort4*)dst)[i] = o;
}

// ---- convert + transpose weights: W[k][ci][co] fp32 -> Wt[k][co][ci] bf16 ----
__global__ void prep_w_kernel(const float* __restrict__ W,
                              unsigned short* __restrict__ Wt) {
    int i = blockIdx.x * blockDim.x + threadIdx.x;
    if (i >= KOFF * 64 * 64) return;
    int k = i >> 12;
    int co = (i >> 6) & 63;
    int ci = i & 63;
    Wt[i] = f2bf(W[(k << 12) + (ci << 6) + co]);
}

// ---- gather-GEMM: Y[i][:] = sum_k X[idx[i][k]][:] @ W[k] ----
// X: [N][64] bf16, nbr: [N][27] int, Wt: [27][64(co)][64(ci)] bf16, Y: [N][64] fp32
#define LDS_PITCH 72  // 64 + 8 ushorts -> 144B rows, 16B aligned, 2-way max bank alias
__global__ __launch_bounds__(256)
void conv_kernel(const unsigned short* __restrict__ X,
                 const int* __restrict__ nbr,
                 const unsigned short* __restrict__ Wt,
                 float* __restrict__ Y,
                 float* __restrict__ stats) {
    __shared__ unsigned short lds_a[64 * LDS_PITCH];
    __shared__ unsigned short lds_w[64 * LDS_PITCH];
    const int tid = threadIdx.x;
    const int wave = tid >> 6;
    const int lane = tid & 63;
    const int quad = lane >> 4;
    const int l16 = lane & 15;
    const int p0 = blockIdx.x * 64;

    // zero the BN stats accumulators for the reduce kernel that follows
    if (blockIdx.x == 0 && tid < 128) stats[tid] = 0.0f;

    const int sr = tid >> 2;   // staging row 0..63 (4 threads per row)
    const int sq = tid & 3;    // 32B quarter of the 128B row

    float4v acc[4];
    #pragma unroll
    for (int t = 0; t < 4; ++t) acc[t] = (float4v){0.f, 0.f, 0.f, 0.f};

    const int a_base = (wave * 16 + l16) * LDS_PITCH + quad * 8;

    for (int k = 0; k < KOFF; ++k) {
        __syncthreads();
        // gather A rows
        int gi = nbr[(p0 + sr) * KOFF + k];
        const uint4* srcA = (const uint4*)(X + ((size_t)gi << 6));
        uint4 a0 = srcA[sq * 2];
        uint4 a1 = srcA[sq * 2 + 1];
        uint4* dstA = (uint4*)(lds_a + sr * LDS_PITCH + sq * 16);
        dstA[0] = a0;
        dstA[1] = a1;
        // stage Wt[k] (co-major, contiguous 8KB)
        const uint4* srcW = (const uint4*)(Wt + ((size_t)k << 12));
        uint4 w0 = srcW[tid];
        uint4 w1 = srcW[tid + 256];
        {
            int r0 = tid >> 3, c0 = (tid & 7) << 3;
            int r1 = (tid + 256) >> 3;
            *(uint4*)(lds_w + r0 * LDS_PITCH + c0) = w0;
            *(uint4*)(lds_w + r1 * LDS_PITCH + c0) = w1;
        }
        __syncthreads();
        // compute: 2 k-steps x 4 n-tiles
        #pragma unroll
        for (int ks = 0; ks < 2; ++ks) {
            short8 afrag = *(const short8*)(lds_a + a_base + ks * 32);
            #pragma unroll
            for (int t = 0; t < 4; ++t) {
                short8 bfrag = *(const short8*)(lds_w + (t * 16 + l16) * LDS_PITCH + ks * 32 + quad * 8);
                acc[t] = __builtin_amdgcn_mfma_f32_16x16x32_bf16(afrag, bfrag, acc[t], 0, 0, 0);
            }
        }
    }
    // write C: row = p0 + wave*16 + quad*4 + reg, col = t*16 + l16
    const int row_base = p0 + wave * 16 + quad * 4;
    #pragma unroll
    for (int t = 0; t < 4; ++t) {
        #pragma unroll
        for (int r = 0; r < 4; ++r) {
            Y[(size_t)(row_base + r) * 64 + t * 16 + l16] = acc[t][r];
        }
    }
}

// ---- per-channel sum / sumsq over rows ----
__global__ void reduce_kernel(const float* __restrict__ Y, float* __restrict__ stats) {
    __shared__ float lsum[256], lsq[256];
    int tid = threadIdx.x;
    int c = tid & 63;
    int g = tid >> 6;
    float s = 0.f, ss = 0.f;
    for (int r = blockIdx.x * 4 + g; r < N_PTS; r += gridDim.x * 4) {
        float v = Y[(size_t)r * 64 + c];
        s += v;
        ss += v * v;
    }
    lsum[tid] = s;
    lsq[tid] = ss;
    __syncthreads();
    if (tid < 64) {
        s = lsum[tid] + lsum[tid + 64] + lsum[tid + 128] + lsum[tid + 192];
        ss = lsq[tid] + lsq[tid + 64] + lsq[tid + 128] + lsq[tid + 192];
        atomicAdd(&stats[c], s);
        atomicAdd(&stats[64 + c], ss);
    }
}

// ---- bn + leakyrelu -> bf16 output (input to next conv) ----
__global__ void bnact_kernel(const float* __restrict__ Y, const float* __restrict__ stats,
                             const float* __restrict__ g, const float* __restrict__ b,
                             unsigned short* __restrict__ Xb, float slope) {
    __shared__ float scale[64], shift[64];
    int tid = threadIdx.x;
    if (tid < 64) {
        float m = stats[tid] * (1.0f / N_PTS);
        float v = stats[64 + tid] * (1.0f / N_PTS) - m * m;
        float rs = rsqrtf(v + 1e-4f);
        float sc = rs * g[tid];
        scale[tid] = sc;
        shift[tid] = b[tid] - m * sc;
    }
    __syncthreads();
    int i = blockIdx.x * blockDim.x + tid;
    const int total = N_PTS * 16;
    if (i >= total) return;
    int cb = (i & 15) << 2;
    float4 y = ((const float4*)Y)[i];
    float o0 = y.x * scale[cb] + shift[cb];
    float o1 = y.y * scale[cb + 1] + shift[cb + 1];
    float o2 = y.z * scale[cb + 2] + shift[cb + 2];
    float o3 = y.w * scale[cb + 3] + shift[cb + 3];
    o0 = o0 >= 0.f ? o0 : slope * o0;
    o1 = o1 >= 0.f ? o1 : slope * o1;
    o2 = o2 >= 0.f ? o2 : slope * o2;
    o3 = o3 >= 0.f ? o3 : slope * o3;
    ushort4 o;
    o.x = f2bf(o0); o.y = f2bf(o1); o.z = f2bf(o2); o.w = f2bf(o3);
    ((ushort4*)Xb)[i] = o;
}

// ---- final: bn3 + residual + leakyrelu(0.333) -> fp32 d_out (in place over Y) ----
__global__ void bnact_final_kernel(float* __restrict__ Y, const float* __restrict__ stats,
                                   const float* __restrict__ g, const float* __restrict__ b,
                                   const unsigned short* __restrict__ res) {
    __shared__ float scale[64], shift[64];
    int tid = threadIdx.x;
    if (tid < 64) {
        float m = stats[tid] * (1.0f / N_PTS);
        float v = stats[64 + tid] * (1.0f / N_PTS) - m * m;
        float rs = rsqrtf(v + 1e-4f);
        float sc = rs * g[tid];
        scale[tid] = sc;
        shift[tid] = b[tid] - m * sc;
    }
    __syncthreads();
    int i = blockIdx.x * blockDim.x + tid;
    const int total = N_PTS * 16;
    if (i >= total) return;
    int cb = (i & 15) << 2;
    float4 y = ((const float4*)Y)[i];
    ushort4 r4 = ((const ushort4*)res)[i];
    float o0 = y.x * scale[cb] + shift[cb] + bf2f(r4.x);
    float o1 = y.y * scale[cb + 1] + shift[cb + 1] + bf2f(r4.y);
    float o2 = y.z * scale[cb + 2] + shift[cb + 2] + bf2f(r4.z);
    float o3 = y.w * scale[cb + 3] + shift[cb + 3] + bf2f(r4.w);
    o0 = o0 >= 0.f ? o0 : 0.333f * o0;
    o1 = o1 >= 0.f ? o1 : 0.333f * o1;
    o2 = o2 >= 0.f ? o2 : 0.333f * o2;
    o3 = o3 >= 0.f ? o3 : 0.333f * o3;
    float4 o; o.x = o0; o.y = o1; o.z = o2; o.w = o3;
    ((float4*)Y)[i] = o;
}

extern "C" void kernel_launch(void* const* d_in, const int* in_sizes, int n_in,
                              void* d_out, int out_size, void* d_ws, size_t ws_size,
                              hipStream_t stream) {
    const float* feat = (const float*)d_in[0];
    const int* nbr = (const int*)d_in[1];
    const float* W1 = (const float*)d_in[2];
    const float* g1 = (const float*)d_in[3];
    const float* b1 = (const float*)d_in[4];
    const float* W2 = (const float*)d_in[5];
    const float* g2 = (const float*)d_in[6];
    const float* b2 = (const float*)d_in[7];
    const float* W3 = (const float*)d_in[8];
    const float* g3 = (const float*)d_in[9];
    const float* b3 = (const float*)d_in[10];
    float* Y = (float*)d_out;

    char* ws = (char*)d_ws;
    const size_t BF_BYTES = (size_t)N_PTS * 64 * 2;  // 51.2 MB
    unsigned short* B0 = (unsigned short*)ws;
    unsigned short* B1 = (unsigned short*)(ws + BF_BYTES);
    unsigned short* Wt = (unsigned short*)(ws + 2 * BF_BYTES);
    float* stats = (float*)(ws + 2 * BF_BYTES + (size_t)3 * KOFF * 4096 * 2);

    const int WSTRIDE = KOFF * 4096;  // 110592

    cast_feat_kernel<<<25000, 256, 0, stream>>>(feat, B0, N_PTS * 16);
    prep_w_kernel<<<(KOFF * 4096 + 255) / 256, 256, 0, stream>>>(W1, Wt);
    prep_w_kernel<<<(KOFF * 4096 + 255) / 256, 256, 0, stream>>>(W2, Wt + WSTRIDE);
    prep_w_kernel<<<(KOFF * 4096 + 255) / 256, 256, 0, stream>>>(W3, Wt + 2 * WSTRIDE);

    // block 1
    conv_kernel<<<N_PTS / 64, 256, 0, stream>>>(B0, nbr, Wt, Y, stats);
    reduce_kernel<<<512, 256, 0, stream>>>(Y, stats);
    bnact_kernel<<<25000, 256, 0, stream>>>(Y, stats, g1, b1, B1, 0.05f);
    // block 2
    conv_kernel<<<N_PTS / 64, 256, 0, stream>>>(B1, nbr, Wt + WSTRIDE, Y, stats);
    reduce_kernel<<<512, 256, 0, stream>>>(Y, stats);
    bnact_kernel<<<25000, 256, 0, stream>>>(Y, stats, g2, b2, B0, 0.05f);
    // block 3 + residual
    conv_kernel<<<N_PTS / 64, 256, 0, stream>>>(B0, nbr, Wt + 2 * WSTRIDE, Y, stats);
    reduce_kernel<<<512, 256, 0, stream>>>(Y, stats);
    bnact_final_kernel<<<25000, 256, 0, stream>>>(Y, stats, g3, b3, B1);
}

// Round 2
// 1001.353 us; speedup vs baseline: 1.1991x; 1.1991x over previous
//
#include <hip/hip_runtime.h>
#include <hip/hip_bf16.h>

#define N_PTS 400000
#define KOFF 27
#define AP 72  // LDS row pitch in ushorts: 144B, breaks pow2 bank aliasing

typedef __attribute__((ext_vector_type(8))) short short8;
typedef __attribute__((ext_vector_type(4))) float float4v;

__device__ __forceinline__ unsigned short f2bf(float f) {
    union { float f; unsigned int u; } a; a.f = f;
    unsigned int u = a.u;
    unsigned int r = (u + 0x7FFFu + ((u >> 16) & 1u)) >> 16;
    return (unsigned short)r;
}

__device__ __forceinline__ float bf2f(unsigned short u) {
    union { unsigned int u; float f; } a; a.u = ((unsigned int)u) << 16;
    return a.f;
}

// ---- cast features fp32 -> bf16 ----
__global__ void cast_feat_kernel(const float* __restrict__ src,
                                 unsigned short* __restrict__ dst, int n4) {
    int i = blockIdx.x * blockDim.x + threadIdx.x;
    if (i >= n4) return;
    const float4* s4 = (const float4*)src;
    float4 v = s4[i];
    ushort4 o;
    o.x = f2bf(v.x); o.y = f2bf(v.y); o.z = f2bf(v.z); o.w = f2bf(v.w);
    ((ushort4*)dst)[i] = o;
}

// ---- one-shot prep: transpose+cast all 3 weight sets, zero all stats ----
__global__ void prep_w_all_kernel(const float* __restrict__ W1,
                                  const float* __restrict__ W2,
                                  const float* __restrict__ W3,
                                  unsigned short* __restrict__ Wt,
                                  float* __restrict__ stats) {
    int i = blockIdx.x * blockDim.x + threadIdx.x;
    if (i < 384) stats[i] = 0.0f;
    if (i >= KOFF * 64 * 64) return;
    int k = i >> 12;
    int co = (i >> 6) & 63;
    int ci = i & 63;
    int src = (k << 12) + (ci << 6) + co;
    const int WS = KOFF * 4096;
    Wt[i] = f2bf(W1[src]);
    Wt[i + WS] = f2bf(W2[src]);
    Wt[i + 2 * WS] = f2bf(W3[src]);
}

// ---- gather-GEMM + fused BN-stats reduction ----
// X: [N][64] bf16, nbr: [N][27] int, Wt: [27][64(co)][64(ci)] bf16
// Y: [N][64] fp32, stats: [128] fp32 (sum, sumsq) pre-zeroed
// Block: 512 threads (8 waves), M-tile = 128 points; register prefetch dbuf.
__global__ __launch_bounds__(512, 6)
void conv_kernel(const unsigned short* __restrict__ X,
                 const int* __restrict__ nbr,
                 const unsigned short* __restrict__ Wt,
                 float* __restrict__ Y,
                 float* __restrict__ stats) {
    __shared__ unsigned short lds_a[128 * AP];  // 18432 B
    __shared__ unsigned short lds_w[64 * AP];   //  9216 B
    const int tid = threadIdx.x;
    const int wave = tid >> 6;
    const int lane = tid & 63;
    const int quad = lane >> 4;
    const int l16 = lane & 15;
    const int p0 = blockIdx.x * 128;

    const int sr = tid >> 2;   // staging row 0..127 (4 threads/row)
    const int sq = tid & 3;    // 32B quarter of the 128B row
    const int wr = tid >> 3;   // W staging row (512 thr x 16B covers 8KB)
    const int wc = (tid & 7) << 3;

    float4v acc[4];
    #pragma unroll
    for (int t = 0; t < 4; ++t) acc[t] = (float4v){0.f, 0.f, 0.f, 0.f};

    // prefetch pipeline: indices 2 ahead, rows/weights 1 ahead
    const long nb = (long)(p0 + sr) * KOFF;
    int gi = nbr[nb];
    int gin = nbr[nb + 1];
    uint4 a0, a1, w0;
    {
        const uint4* srcA = (const uint4*)(X + ((size_t)gi << 6)) + sq * 2;
        a0 = srcA[0];
        a1 = srcA[1];
        w0 = ((const uint4*)Wt)[tid];
    }

    for (int k = 0; k < KOFF; ++k) {
        __syncthreads();  // previous iteration's compute done reading LDS
        *(uint4*)(lds_a + sr * AP + sq * 16) = a0;
        *(uint4*)(lds_a + sr * AP + sq * 16 + 8) = a1;
        *(uint4*)(lds_w + wr * AP + wc) = w0;
        if (k < KOFF - 1) {
            const uint4* srcA = (const uint4*)(X + ((size_t)gin << 6)) + sq * 2;
            a0 = srcA[0];
            a1 = srcA[1];
            w0 = ((const uint4*)(Wt + (((size_t)(k + 1)) << 12)))[tid];
            gin = (k < KOFF - 2) ? nbr[nb + k + 2] : 0;
        }
        __syncthreads();  // staged data visible
        const int abase = (wave * 16 + l16) * AP + quad * 8;
        #pragma unroll
        for (int ks = 0; ks < 2; ++ks) {
            short8 af = *(const short8*)(lds_a + abase + ks * 32);
            #pragma unroll
            for (int t = 0; t < 4; ++t) {
                short8 bf = *(const short8*)(lds_w + (t * 16 + l16) * AP + ks * 32 + quad * 8);
                acc[t] = __builtin_amdgcn_mfma_f32_16x16x32_bf16(af, bf, acc[t], 0, 0, 0);
            }
        }
    }

    // write C: row = p0 + wave*16 + quad*4 + r, col = t*16 + l16
    const int row_base = p0 + wave * 16 + quad * 4;
    #pragma unroll
    for (int t = 0; t < 4; ++t) {
        #pragma unroll
        for (int r = 0; r < 4; ++r) {
            Y[(size_t)(row_base + r) * 64 + t * 16 + l16] = acc[t][r];
        }
    }

    // fused BN stats: per-lane over 4 rows -> shuffle across quads -> LDS -> 1 atomic/block
    __syncthreads();  // done reading lds_w; reuse as fp32 scratch
    float* red = (float*)lds_w;
    if (tid < 128) red[tid] = 0.0f;
    __syncthreads();
    #pragma unroll
    for (int t = 0; t < 4; ++t) {
        float s = acc[t][0] + acc[t][1] + acc[t][2] + acc[t][3];
        float ss = acc[t][0] * acc[t][0] + acc[t][1] * acc[t][1] +
                   acc[t][2] * acc[t][2] + acc[t][3] * acc[t][3];
        s += __shfl_down(s, 32);
        s += __shfl_down(s, 16);
        ss += __shfl_down(ss, 32);
        ss += __shfl_down(ss, 16);
        if (lane < 16) {
            atomicAdd(&red[t * 16 + l16], s);
            atomicAdd(&red[64 + t * 16 + l16], ss);
        }
    }
    __syncthreads();
    if (tid < 128) atomicAdd(&stats[tid], red[tid]);
}

// ---- bn + leakyrelu -> bf16 output (input to next conv) ----
__global__ void bnact_kernel(const float* __restrict__ Y, const float* __restrict__ stats,
                             const float* __restrict__ g, const float* __restrict__ b,
                             unsigned short* __restrict__ Xb, float slope) {
    __shared__ float scale[64], shift[64];
    int tid = threadIdx.x;
    if (tid < 64) {
        float m = stats[tid] * (1.0f / N_PTS);
        float v = stats[64 + tid] * (1.0f / N_PTS) - m * m;
        float rs = rsqrtf(v + 1e-4f);
        float sc = rs * g[tid];
        scale[tid] = sc;
        shift[tid] = b[tid] - m * sc;
    }
    __syncthreads();
    int i = blockIdx.x * blockDim.x + tid;
    const int total = N_PTS * 16;
    if (i >= total) return;
    int cb = (i & 15) << 2;
    float4 y = ((const float4*)Y)[i];
    float o0 = y.x * scale[cb] + shift[cb];
    float o1 = y.y * scale[cb + 1] + shift[cb + 1];
    float o2 = y.z * scale[cb + 2] + shift[cb + 2];
    float o3 = y.w * scale[cb + 3] + shift[cb + 3];
    o0 = o0 >= 0.f ? o0 : slope * o0;
    o1 = o1 >= 0.f ? o1 : slope * o1;
    o2 = o2 >= 0.f ? o2 : slope * o2;
    o3 = o3 >= 0.f ? o3 : slope * o3;
    ushort4 o;
    o.x = f2bf(o0); o.y = f2bf(o1); o.z = f2bf(o2); o.w = f2bf(o3);
    ((ushort4*)Xb)[i] = o;
}

// ---- final: bn3 + residual + leakyrelu(0.333) -> fp32 d_out (in place over Y) ----
__global__ void bnact_final_kernel(float* __restrict__ Y, const float* __restrict__ stats,
                                   const float* __restrict__ g, const float* __restrict__ b,
                                   const unsigned short* __restrict__ res) {
    __shared__ float scale[64], shift[64];
    int tid = threadIdx.x;
    if (tid < 64) {
        float m = stats[tid] * (1.0f / N_PTS);
        float v = stats[64 + tid] * (1.0f / N_PTS) - m * m;
        float rs = rsqrtf(v + 1e-4f);
        float sc = rs * g[tid];
        scale[tid] = sc;
        shift[tid] = b[tid] - m * sc;
    }
    __syncthreads();
    int i = blockIdx.x * blockDim.x + tid;
    const int total = N_PTS * 16;
    if (i >= total) return;
    int cb = (i & 15) << 2;
    float4 y = ((const float4*)Y)[i];
    ushort4 r4 = ((const ushort4*)res)[i];
    float o0 = y.x * scale[cb] + shift[cb] + bf2f(r4.x);
    float o1 = y.y * scale[cb + 1] + shift[cb + 1] + bf2f(r4.y);
    float o2 = y.z * scale[cb + 2] + shift[cb + 2] + bf2f(r4.z);
    float o3 = y.w * scale[cb + 3] + shift[cb + 3] + bf2f(r4.w);
    o0 = o0 >= 0.f ? o0 : 0.333f * o0;
    o1 = o1 >= 0.f ? o1 : 0.333f * o1;
    o2 = o2 >= 0.f ? o2 : 0.333f * o2;
    o3 = o3 >= 0.f ? o3 : 0.333f * o3;
    float4 o; o.x = o0; o.y = o1; o.z = o2; o.w = o3;
    ((float4*)Y)[i] = o;
}

extern "C" void kernel_launch(void* const* d_in, const int* in_sizes, int n_in,
                              void* d_out, int out_size, void* d_ws, size_t ws_size,
                              hipStream_t stream) {
    const float* feat = (const float*)d_in[0];
    const int* nbr = (const int*)d_in[1];
    const float* W1 = (const float*)d_in[2];
    const float* g1 = (const float*)d_in[3];
    const float* b1 = (const float*)d_in[4];
    const float* W2 = (const float*)d_in[5];
    const float* g2 = (const float*)d_in[6];
    const float* b2 = (const float*)d_in[7];
    const float* W3 = (const float*)d_in[8];
    const float* g3 = (const float*)d_in[9];
    const float* b3 = (const float*)d_in[10];
    float* Y = (float*)d_out;

    char* ws = (char*)d_ws;
    const size_t BF_BYTES = (size_t)N_PTS * 64 * 2;  // 51.2 MB
    unsigned short* B0 = (unsigned short*)ws;
    unsigned short* B1 = (unsigned short*)(ws + BF_BYTES);
    unsigned short* Wt = (unsigned short*)(ws + 2 * BF_BYTES);
    float* stats = (float*)(ws + 2 * BF_BYTES + (size_t)3 * KOFF * 4096 * 2);

    const int WSTRIDE = KOFF * 4096;  // 110592

    cast_feat_kernel<<<25000, 256, 0, stream>>>(feat, B0, N_PTS * 16);
    prep_w_all_kernel<<<(KOFF * 4096 + 255) / 256, 256, 0, stream>>>(W1, W2, W3, Wt, stats);

    // block 1
    conv_kernel<<<N_PTS / 128, 512, 0, stream>>>(B0, nbr, Wt, Y, stats);
    bnact_kernel<<<25000, 256, 0, stream>>>(Y, stats, g1, b1, B1, 0.05f);
    // block 2
    conv_kernel<<<N_PTS / 128, 512, 0, stream>>>(B1, nbr, Wt + WSTRIDE, Y, stats + 128);
    bnact_kernel<<<25000, 256, 0, stream>>>(Y, stats + 128, g2, b2, B0, 0.05f);
    // block 3 + residual
    conv_kernel<<<N_PTS / 128, 512, 0, stream>>>(B0, nbr, Wt + 2 * WSTRIDE, Y, stats + 256);
    bnact_final_kernel<<<25000, 256, 0, stream>>>(Y, stats + 256, g3, b3, B1);
}